// Round 5
// baseline (3114.045 us; speedup 1.0000x reference)
//
#include <hip/hip_runtime.h>

#define NN     100000
#define NB     1563          // ceil(100000 / 64)
#define LN_EPS 1e-5f
#define SLOPE  0.01f

typedef __bf16 bf16x8 __attribute__((ext_vector_type(8)));
typedef float  f32x4  __attribute__((ext_vector_type(4)));
typedef unsigned short u16;
typedef unsigned int   u32;

union Pack8 { uint4 u4; bf16x8 bf; u16 s[8]; };

__device__ __forceinline__ u16 f2bf(float x){
    u32 b = __float_as_uint(x);
    b += 0x7fffu + ((b >> 16) & 1u);
    return (u16)(b >> 16);
}
__device__ __forceinline__ float bf2f(u32 s){
    return __uint_as_float(s << 16);
}

// Pack w[1024][1024] fp32 (row = output col i, inner = k) into bf16 B-fragment
// order: Wp[k>>5][i][k&31]; B-frag load for (col,ks) is uint4 (ks*1024+col)*4+q.
__global__ __launch_bounds__(1024) void prep_weights(
    const float* __restrict__ wa, const float* __restrict__ wb,
    const float* __restrict__ wc, const float* __restrict__ wd,
    u16* __restrict__ dst)
{
    int m = blockIdx.y;
    const float* src = (m==0)? wa : (m==1)? wb : (m==2)? wc : wd;
    u16* d = dst + (size_t)m * (1024u*1024u);
    int tid = blockIdx.x * blockDim.x + threadIdx.x;   // 0..131071
    int sub = tid & 3;
    int row = (tid >> 2) & 1023;
    int kb  = tid >> 12;                               // 0..31
    const float4* s4 = (const float4*)(src + row*1024 + kb*32 + sub*8);
    float4 a = s4[0], b = s4[1];
    Pack8 p;
    p.s[0]=f2bf(a.x); p.s[1]=f2bf(a.y); p.s[2]=f2bf(a.z); p.s[3]=f2bf(a.w);
    p.s[4]=f2bf(b.x); p.s[5]=f2bf(b.y); p.s[6]=f2bf(b.z); p.s[7]=f2bf(b.w);
    ((uint4*)d)[(kb*1024 + row)*4 + sub] = p.u4;
}

// 64-col GEMM pass: one wave computes 4 col-tiles (cols C0..C0+63) for all 64
// nodes. B-fragments stream from L2 through a DEPTH-4 register ring: loads
// for iteration ks+4 are issued at ks, so ~16 loads stay in flight through
// the MFMA phase (the round-4 batch-then-wait loop had them in flight only
// during the stall window -> MLP-starved). A-frags read JIT from LDS.
__device__ __forceinline__ void gemm_quad4(
    const u16* __restrict__ Wp, const u16* xs,
    int C0, int lane15, int q, f32x4 acc[4][4])
{
    const uint4* Wp4 = (const uint4*)Wp + (C0 + lane15)*4 + q;
    const uint4* ab  = (const uint4*)xs + q*64 + lane15;
    uint4 ring[4][4];
    #pragma unroll
    for (int i=0;i<4;++i)
      #pragma unroll
      for (int t=0;t<4;++t) ring[i][t] = Wp4[i*4096 + t*64];
    #pragma unroll
    for (int t=0;t<4;++t)
      #pragma unroll
      for (int rt=0;rt<4;++rt) acc[t][rt] = (f32x4){0.f,0.f,0.f,0.f};
    for (int kb=0; kb<8; ++kb){
        #pragma unroll
        for (int kk=0; kk<4; ++kk){
            const int ks = kb*4 + kk;
            Pack8 a[4];
            #pragma unroll
            for (int rt=0;rt<4;++rt) a[rt].u4 = ab[ks*256 + rt*16];
            #pragma unroll
            for (int t=0;t<4;++t){
                Pack8 bb; bb.u4 = ring[kk][t];
                #pragma unroll
                for (int rt=0;rt<4;++rt)
                    acc[t][rt] = __builtin_amdgcn_mfma_f32_16x16x32_bf16(a[rt].bf, bb.bf, acc[t][rt], 0,0,0);
            }
            if (kb < 7){
                #pragma unroll
                for (int t=0;t<4;++t) ring[kk][t] = Wp4[(ks+4)*4096 + t*64];
            }
        }
    }
}

// Multi-value wave fold: lane15==l ends with totals for value-index l in [0].
__device__ __forceinline__ void fold16(float p_[16], float pp_[16], int lane15){
    #pragma unroll
    for (int m=8; m>=1; m>>=1){
        const bool hi = (lane15 & m) != 0;
        #pragma unroll
        for (int i=0; i<m; ++i){
            float sp = hi ? p_[i]  : p_[i+m];
            float kp = hi ? p_[i+m]  : p_[i];
            p_[i]  = kp + __shfl_xor(sp, m);
            float sq = hi ? pp_[i] : pp_[i+m];
            float kq = hi ? pp_[i+m] : pp_[i];
            pp_[i] = kq + __shfl_xor(sq, m);
        }
    }
}

// LDS layout (floats):
//   [0, 32832)       : xs (bf16 activations, 131072 B) / later sbuf (fp32 h2)
//   [32832, +64*VSTR): vbuf, per-node padded v rows
//   then 128 floats  : stats (64 nodes x {sum, sumsq})
template<int MDIM>
__global__ __launch_bounds__(512, 2) void gal_fused(
    const float* __restrict__ f,
    const float* __restrict__ ln1g, const float* __restrict__ ln1b,
    const float* __restrict__ ln2g, const float* __restrict__ ln2b,
    const float* __restrict__ b2,
    const u16* __restrict__ Wp1, const u16* __restrict__ Wp2,
    float* __restrict__ outp)
{
    extern __shared__ char smem[];
    constexpr int VSTR = 32*MDIM + 4;           // padded node stride (floats)
    constexpr int SBS  = 64*32 + 4;             // sbuf per-slot stride = 2052
    u16*   xs    = (u16*)smem;
    float* sbuf  = (float*)smem;
    float* vbuf  = (float*)smem + 32832;
    float* stats = (float*)smem + 32832 + 64*VSTR;

    const int tid    = threadIdx.x;            // 0..511
    const int lane   = tid & 63;
    const int wv     = tid >> 6;               // wave 0..7
    const int lane15 = lane & 15;
    const int q      = lane >> 4;
    const int node0  = blockIdx.x * 64;

    // ---- Phase 0: zero stats, stage v tile (float4, padded, zero-fill)
    if (tid < 128) stats[tid] = 0.f;
    {
        float4* vbuf4 = (float4*)vbuf;
        const int gv4  = node0*8*MDIM;          // block base in float4 units
        const int lim4 = NN*8*MDIM;
        for (int i = tid; i < 64*8*MDIM; i += 512){
            int nd = i / (8*MDIM);
            int r4 = i - nd*(8*MDIM);
            float4 val = (gv4 + i < lim4) ? ((const float4*)f)[gv4 + i]
                                          : (float4){0.f,0.f,0.f,0.f};
            vbuf4[nd*(VSTR/4) + r4] = val;
        }
    }
    __syncthreads();

    // ---- Phase 1: gram + LN1 + lrelu -> xs (bf16, [k>>3][node][k&7])
    // 8 threads per node; thread j owns k = j*128 .. j*128+127 (a-rows j*4..+3)
    {
        const int n = tid >> 3;          // node
        const int j = tid & 7;
        const float* vn = vbuf + n*VSTR;
        float va[4][MDIM];
        #pragma unroll
        for (int i=0;i<4;++i)
          #pragma unroll
          for (int c=0;c<MDIM;++c) va[i][c] = vn[(j*4+i)*MDIM+c];
        float sum=0.f, ssum=0.f;
        #pragma unroll
        for (int b=0;b<32;++b){
            float vb[MDIM];
            #pragma unroll
            for (int c=0;c<MDIM;++c) vb[c] = vn[b*MDIM+c];
            #pragma unroll
            for (int i=0;i<4;++i){
                float d=0.f;
                #pragma unroll
                for (int c=0;c<MDIM;++c) d += va[i][c]*vb[c];
                sum += d; ssum += d*d;
            }
        }
        #pragma unroll
        for (int st=1; st<8; st<<=1){ sum += __shfl_xor(sum, st); ssum += __shfl_xor(ssum, st); }
        float mu   = sum * (1.f/1024.f);
        float rstd = rsqrtf(ssum*(1.f/1024.f) - mu*mu + LN_EPS);
        #pragma unroll
        for (int jb=0;jb<16;++jb){
            const int k0 = j*128 + jb*8;
            float4 ga = ((const float4*)(ln1g + k0))[0];
            float4 gb = ((const float4*)(ln1g + k0))[1];
            float4 ba = ((const float4*)(ln1b + k0))[0];
            float4 bb = ((const float4*)(ln1b + k0))[1];
            float gg[8]  = {ga.x,ga.y,ga.z,ga.w,gb.x,gb.y,gb.z,gb.w};
            float bbv[8] = {ba.x,ba.y,ba.z,ba.w,bb.x,bb.y,bb.z,bb.w};
            Pack8 p;
            const int ai = jb >> 2;
            #pragma unroll
            for (int l=0;l<8;++l){
                int b = (jb*8+l) & 31;
                float d = 0.f;
                #pragma unroll
                for (int c=0;c<MDIM;++c) d += va[ai][c]*vn[b*MDIM+c];
                float x = (d - mu)*rstd*gg[l] + bbv[l];
                x = (x >= 0.f)? x : SLOPE*x;
                p.s[l] = f2bf(x);
            }
            ((uint4*)xs)[(j*16+jb)*64 + n] = p.u4;
        }
    }
    __syncthreads();

    // ---- Phase 2: h1 = x1 @ W1^T in two 64-col passes. Pass-0 h1 stashed
    // bf16 (32 regs); pass-1 acc stays live into phase 3. One atomic pair.
    f32x4 acc[4][4];
    u32   h1s[4][4][2];
    float myp, mypp;
    {
        gemm_quad4(Wp1, xs, wv*64, lane15, q, acc);      // pass 0
        float p_[16], pp_[16];
        #pragma unroll
        for (int idx=0; idx<16; ++idx){
            int rt = idx>>2, rr = idx&3;
            float s=0.f, s2=0.f;
            #pragma unroll
            for (int t=0; t<4; ++t){ float h = acc[t][rt][rr]; s += h; s2 += h*h; }
            p_[idx] = s; pp_[idx] = s2;
        }
        fold16(p_, pp_, lane15);
        myp = p_[0]; mypp = pp_[0];
        #pragma unroll
        for (int t=0; t<4; ++t)
          #pragma unroll
          for (int rt=0; rt<4; ++rt){
            h1s[t][rt][0] = (u32)f2bf(acc[t][rt][0]) | ((u32)f2bf(acc[t][rt][1])<<16);
            h1s[t][rt][1] = (u32)f2bf(acc[t][rt][2]) | ((u32)f2bf(acc[t][rt][3])<<16);
          }
    }
    gemm_quad4(Wp1, xs, 512 + wv*64, lane15, q, acc);    // pass 1
    {
        float p_[16], pp_[16];
        #pragma unroll
        for (int idx=0; idx<16; ++idx){
            int rt = idx>>2, rr = idx&3;
            float s=0.f, s2=0.f;
            #pragma unroll
            for (int t=0; t<4; ++t){ float h = acc[t][rt][rr]; s += h; s2 += h*h; }
            p_[idx] = s; pp_[idx] = s2;
        }
        fold16(p_, pp_, lane15);
        int nd0 = (lane15>>2)*16 + q*4 + (lane15&3);
        atomicAdd(&stats[2*nd0],   myp + p_[0]);
        atomicAdd(&stats[2*nd0+1], mypp + pp_[0]);
    }
    __syncthreads();   // stats final AND all GEMM1 xs reads drained

    // ---- Phase 3: LN2 + lrelu -> x2 into xs (pass1 from acc, pass0 from h1s)
    {
        float gA[4], bA[4], gB[4], bB[4];
        #pragma unroll
        for (int t=0; t<4; ++t){
            int colA = wv*64 + t*16 + lane15;
            int colB = 512 + colA;
            gA[t] = ln2g[colA]; bA[t] = ln2b[colA];
            gB[t] = ln2g[colB]; bB[t] = ln2b[colB];
        }
        #pragma unroll
        for (int rt=0; rt<4; ++rt)
          #pragma unroll
          for (int rr=0; rr<4; ++rr){
            int nd = rt*16 + q*4 + rr;
            float mu   = stats[2*nd]*(1.f/1024.f);
            float rstd = rsqrtf(stats[2*nd+1]*(1.f/1024.f) - mu*mu + LN_EPS);
            #pragma unroll
            for (int t=0; t<4; ++t){
                int colA = wv*64 + t*16 + lane15;
                u32 u = h1s[t][rt][rr>>1];
                float h = bf2f((rr&1)? (u>>16) : (u & 0xffffu));
                float x = (h - mu)*rstd*gA[t] + bA[t];
                x = (x >= 0.f)? x : SLOPE*x;
                xs[(colA>>3)*512 + nd*8 + (colA&7)] = f2bf(x);
                int colB = 512 + colA;
                float h2 = acc[t][rt][rr];
                float x2 = (h2 - mu)*rstd*gB[t] + bB[t];
                x2 = (x2 >= 0.f)? x2 : SLOPE*x2;
                xs[(colB>>3)*512 + nd*8 + (colB&7)] = f2bf(x2);
            }
          }
    }
    __syncthreads();

    // ---- Phase 4: h2 = x2 @ W2^T + b2 in two passes; pass-0 stashed bf16.
    // Then per pass: stage 16 a-strips into retired xs, softmax + attn @ v.
    u32 h2s[4][4][2];
    {
        gemm_quad4(Wp2, xs, wv*64, lane15, q, acc);      // pass 0
        float biasA[4];
        #pragma unroll
        for (int t=0; t<4; ++t) biasA[t] = b2[wv*64 + t*16 + lane15];
        #pragma unroll
        for (int t=0; t<4; ++t)
          #pragma unroll
          for (int rt=0; rt<4; ++rt){
            h2s[t][rt][0] = (u32)f2bf(acc[t][rt][0]+biasA[t]) | ((u32)f2bf(acc[t][rt][1]+biasA[t])<<16);
            h2s[t][rt][1] = (u32)f2bf(acc[t][rt][2]+biasA[t]) | ((u32)f2bf(acc[t][rt][3]+biasA[t])<<16);
          }
    }
    gemm_quad4(Wp2, xs, 512 + wv*64, lane15, q, acc);    // pass 1
    {
        float biasB[4];
        #pragma unroll
        for (int t=0; t<4; ++t) biasB[t] = b2[512 + wv*64 + t*16 + lane15];
        #pragma unroll
        for (int t=0; t<4; ++t)
          #pragma unroll
          for (int rt=0; rt<4; ++rt)
            #pragma unroll
            for (int rr=0; rr<4; ++rr) acc[t][rt][rr] += biasB[t];
    }
    __syncthreads();   // all xs reads complete before sbuf overwrite

    #pragma unroll
    for (int ps=0; ps<2; ++ps){
        // stage: wave wv's strips -> slots wv*2+u (u = t>>1), b = (t&1)*16+lane15
        #pragma unroll
        for (int t=0; t<4; ++t){
            const int slot = wv*2 + (t>>1);
            const int bcol = (t&1)*16 + lane15;
            #pragma unroll
            for (int rt=0; rt<4; ++rt)
              #pragma unroll
              for (int rr=0; rr<4; ++rr){
                int nd = rt*16 + q*4 + rr;
                float val;
                if (ps==0){
                    u32 u = h2s[t][rt][rr>>1];
                    val = bf2f((rr&1)? (u>>16) : (u & 0xffffu));
                } else {
                    val = acc[t][rt][rr];
                }
                sbuf[slot*SBS + nd*32 + bcol] = val;
              }
        }
        __syncthreads();
        // consume: 1024 (node, strip) tasks over 512 threads, 2 reps
        #pragma unroll
        for (int rep=0; rep<2; ++rep){
            const int pi = tid + rep*512;
            const int nd = pi >> 4;
            const int s  = pi & 15;
            const float* hp = sbuf + s*SBS + nd*32;
            float e[32];
            #pragma unroll
            for (int r=0;r<8;++r){
                float4 v4 = ((const float4*)hp)[r];
                e[4*r]=v4.x; e[4*r+1]=v4.y; e[4*r+2]=v4.z; e[4*r+3]=v4.w;
            }
            float mx = e[0];
            #pragma unroll
            for (int b=1;b<32;++b) mx = fmaxf(mx, e[b]);
            float sm = 0.f;
            #pragma unroll
            for (int b=0;b<32;++b){ e[b] = __expf(e[b]-mx); sm += e[b]; }
            float inv = 1.f / sm;
            float oacc[MDIM];
            #pragma unroll
            for (int c=0;c<MDIM;++c) oacc[c]=0.f;
            const float4* vr = (const float4*)(vbuf + nd*VSTR);
            #pragma unroll
            for (int r=0; r<8*MDIM; ++r){
                float4 v4 = vr[r];
                #pragma unroll
                for (int t=0;t<4;++t){
                    const int fi = 4*r+t;
                    const int b  = fi/MDIM;
                    const int c  = fi - b*MDIM;
                    float comp = (t==0)?v4.x:(t==1)?v4.y:(t==2)?v4.z:v4.w;
                    oacc[c] += e[b]*comp;
                }
            }
            int ng = node0 + nd;
            if (ng < NN){
                const int a = s + ps*16;
                #pragma unroll
                for (int c=0;c<MDIM;++c)
                    outp[((size_t)ng*32 + a)*MDIM + c] = oacc[c]*inv;
            }
        }
        if (ps==0) __syncthreads();   // WAR on sbuf before pass-1 staging
    }
}

extern "C" void kernel_launch(void* const* d_in, const int* in_sizes, int n_in,
                              void* d_out, int out_size, void* d_ws, size_t ws_size,
                              hipStream_t stream)
{
    const float* f0    = (const float*)d_in[0];
    const float* f1    = (const float*)d_in[1];
    const float* ln1g0 = (const float*)d_in[2];
    const float* ln1b0 = (const float*)d_in[3];
    const float* w1_0  = (const float*)d_in[4];
    const float* ln2g0 = (const float*)d_in[5];
    const float* ln2b0 = (const float*)d_in[6];
    const float* w2_0  = (const float*)d_in[7];
    const float* b2_0  = (const float*)d_in[8];
    const float* ln1g1 = (const float*)d_in[9];
    const float* ln1b1 = (const float*)d_in[10];
    const float* w1_1  = (const float*)d_in[11];
    const float* ln2g1 = (const float*)d_in[12];
    const float* ln2b1 = (const float*)d_in[13];
    const float* w2_1  = (const float*)d_in[14];
    const float* b2_1  = (const float*)d_in[15];
    float* out = (float*)d_out;
    u16* wp = (u16*)d_ws;    // 4 packed matrices x 2 MB = 8 MB scratch

    const int smem1 = (32832 + 64*(32*1+4) + 128)*4;   // 141056
    const int smem3 = (32832 + 64*(32*3+4) + 128)*4;   // 157440
    (void)hipFuncSetAttribute(reinterpret_cast<const void*>(&gal_fused<1>),
                              hipFuncAttributeMaxDynamicSharedMemorySize, smem1);
    (void)hipFuncSetAttribute(reinterpret_cast<const void*>(&gal_fused<3>),
                              hipFuncAttributeMaxDynamicSharedMemorySize, smem3);

    prep_weights<<<dim3(128,4), 1024, 0, stream>>>(w1_0, w2_0, w1_1, w2_1, wp);
    gal_fused<1><<<NB, 512, smem1, stream>>>(f0, ln1g0, ln1b0, ln2g0, ln2b0, b2_0,
                                             wp,            wp + 1048576, out);
    gal_fused<3><<<NB, 512, smem3, stream>>>(f1, ln1g1, ln1b1, ln2g1, ln2b1, b2_1,
                                             wp + 2097152,  wp + 3145728, out + (size_t)NN*32);
}

// Round 6
// 1372.322 us; speedup vs baseline: 2.2692x; 2.2692x over previous
//
#include <hip/hip_runtime.h>

#define NN     100000
#define NB     1563          // ceil(100000 / 64)
#define LN_EPS 1e-5f
#define SLOPE  0.01f

typedef __bf16 bf16x8 __attribute__((ext_vector_type(8)));
typedef float  f32x4  __attribute__((ext_vector_type(4)));
typedef unsigned short u16;
typedef unsigned int   u32;

union Pack8 { uint4 u4; bf16x8 bf; u16 s[8]; };

__device__ __forceinline__ u16 f2bf(float x){
    u32 b = __float_as_uint(x);
    b += 0x7fffu + ((b >> 16) & 1u);
    return (u16)(b >> 16);
}

// Pack w[1024][1024] fp32 (row = output col i, inner = k) into bf16 B-fragment
// order: Wp[k>>5][i][k&31]; B-frag load for (col,ks) is uint4 (ks*1024+col)*4+q.
__global__ __launch_bounds__(1024) void prep_weights(
    const float* __restrict__ wa, const float* __restrict__ wb,
    const float* __restrict__ wc, const float* __restrict__ wd,
    u16* __restrict__ dst)
{
    int m = blockIdx.y;
    const float* src = (m==0)? wa : (m==1)? wb : (m==2)? wc : wd;
    u16* d = dst + (size_t)m * (1024u*1024u);
    int tid = blockIdx.x * blockDim.x + threadIdx.x;   // 0..131071
    int sub = tid & 3;
    int row = (tid >> 2) & 1023;
    int kb  = tid >> 12;                               // 0..31
    const float4* s4 = (const float4*)(src + row*1024 + kb*32 + sub*8);
    float4 a = s4[0], b = s4[1];
    Pack8 p;
    p.s[0]=f2bf(a.x); p.s[1]=f2bf(a.y); p.s[2]=f2bf(a.z); p.s[3]=f2bf(a.w);
    p.s[4]=f2bf(b.x); p.s[5]=f2bf(b.y); p.s[6]=f2bf(b.z); p.s[7]=f2bf(b.w);
    ((uint4*)d)[(kb*1024 + row)*4 + sub] = p.u4;
}

// One wave computes 4 col-tiles (cols C0..C0+63) for all 64 nodes, in ONE
// pass. 16 MFMA per {4 B-loads (L2, JIT batch) + 4 A ds_read_b128}. Register
// shape chosen for the 16-wave/128-reg budget: acc = 64 AGPR, working arch
// VGPRs ~50 -> no spill, no stash, no prefetch ring (r3/r5 lessons).
__device__ __forceinline__ void gemm_quad1(
    const u16* __restrict__ Wp, const u16* xs,
    int C0, int lane15, int q, f32x4 acc[4][4])
{
    const uint4* bb = (const uint4*)Wp + (C0 + lane15)*4 + q;
    const uint4* ab = (const uint4*)xs + q*64 + lane15;
    #pragma unroll
    for (int t=0; t<4; ++t)
      #pragma unroll
      for (int rt=0; rt<4; ++rt)
        acc[t][rt] = (f32x4){0.f,0.f,0.f,0.f};
    #pragma unroll 2
    for (int ks=0; ks<32; ++ks){
        Pack8 b[4], a[4];
        #pragma unroll
        for (int t=0; t<4; ++t) b[t].u4 = bb[ks*4096 + t*64];
        #pragma unroll
        for (int rt=0; rt<4; ++rt) a[rt].u4 = ab[ks*256 + rt*16];
        #pragma unroll
        for (int t=0; t<4; ++t)
          #pragma unroll
          for (int rt=0; rt<4; ++rt)
            acc[t][rt] = __builtin_amdgcn_mfma_f32_16x16x32_bf16(a[rt].bf, b[t].bf, acc[t][rt], 0,0,0);
    }
}

// LDS layout (floats):
//   [0, 32832)       : xs (bf16 activations, 131072 B) / later sbuf (fp32 h2)
//   [32832, +64*VSTR): vbuf, per-node padded v rows
//   then 128 floats  : stats (64 nodes x {sum, sumsq})
template<int MDIM>
__global__ __launch_bounds__(1024, 4) void gal_fused(
    const float* __restrict__ f,
    const float* __restrict__ ln1g, const float* __restrict__ ln1b,
    const float* __restrict__ ln2g, const float* __restrict__ ln2b,
    const float* __restrict__ b2,
    const u16* __restrict__ Wp1, const u16* __restrict__ Wp2,
    float* __restrict__ outp)
{
    extern __shared__ char smem[];
    constexpr int VSTR = 32*MDIM + 4;           // padded node stride (floats)
    constexpr int SBS  = 64*32 + 4;             // sbuf per-slot stride = 2052
    u16*   xs    = (u16*)smem;
    float* sbuf  = (float*)smem;
    float* vbuf  = (float*)smem + 32832;
    float* stats = (float*)smem + 32832 + 64*VSTR;

    const int tid    = threadIdx.x;            // 0..1023
    const int lane   = tid & 63;
    const int wv     = tid >> 6;               // wave 0..15
    const int lane15 = lane & 15;
    const int q      = lane >> 4;
    const int node0  = blockIdx.x * 64;

    // ---- Phase 0: zero stats, stage v tile (float4, padded, zero-fill)
    if (tid < 128) stats[tid] = 0.f;
    {
        float4* vbuf4 = (float4*)vbuf;
        const int gv4  = node0*8*MDIM;          // block base in float4 units
        const int lim4 = NN*8*MDIM;
        for (int i = tid; i < 64*8*MDIM; i += 1024){
            int nd = i / (8*MDIM);
            int r4 = i - nd*(8*MDIM);
            float4 val = (gv4 + i < lim4) ? ((const float4*)f)[gv4 + i]
                                          : (float4){0.f,0.f,0.f,0.f};
            vbuf4[nd*(VSTR/4) + r4] = val;
        }
    }
    __syncthreads();

    // ---- Phase 1: gram + LN1 + lrelu -> xs (bf16, [k>>3][node][k&7])
    // 16 threads/node; thread j owns k = j*64..j*64+63. Dots recomputed in
    // the pack pass (no 64-float array). Scalar ln1g/ln1b loads (reg-lean).
    {
        const int n = tid >> 4;          // node
        const int j = tid & 15;
        const float* vn = vbuf + n*VSTR;
        float va[2][MDIM];
        #pragma unroll
        for (int c=0;c<MDIM;++c){ va[0][c]=vn[(j*2)*MDIM+c]; va[1][c]=vn[(j*2+1)*MDIM+c]; }
        float sum=0.f, ssum=0.f;
        #pragma unroll
        for (int b=0;b<32;++b){
            float d0=0.f, d1=0.f;
            #pragma unroll
            for (int c=0;c<MDIM;++c){ float vb = vn[b*MDIM+c]; d0 += va[0][c]*vb; d1 += va[1][c]*vb; }
            sum += d0+d1; ssum += d0*d0 + d1*d1;
        }
        #pragma unroll
        for (int st=1; st<16; st<<=1){ sum += __shfl_xor(sum, st); ssum += __shfl_xor(ssum, st); }
        float mu   = sum * (1.f/1024.f);
        float rstd = rsqrtf(ssum*(1.f/1024.f) - mu*mu + LN_EPS);
        #pragma unroll
        for (int jb=0;jb<8;++jb){
            Pack8 p;
            const int ai = jb >> 2;
            #pragma unroll
            for (int l=0;l<8;++l){
                int b = (jb*8+l) & 31;
                float d = 0.f;
                #pragma unroll
                for (int c=0;c<MDIM;++c) d += va[ai][c]*vn[b*MDIM+c];
                int k = j*64 + jb*8 + l;
                float x = (d - mu)*rstd*ln1g[k] + ln1b[k];
                x = (x >= 0.f)? x : SLOPE*x;
                p.s[l] = f2bf(x);
            }
            ((uint4*)xs)[(j*8+jb)*64 + n] = p.u4;
        }
    }
    __syncthreads();

    // ---- Phase 2: h1 = x1 @ W1^T, one pass, wave wv owns cols wv*64..+63.
    // Stats via fold-tree + one atomic pair; acc stays live in AGPRs.
    {
        f32x4 acc[4][4];
        gemm_quad1(Wp1, xs, wv*64, lane15, q, acc);
        {
            float p_[16], pp_[16];
            #pragma unroll
            for (int idx=0; idx<16; ++idx){
                int rt = idx>>2, rr = idx&3;
                float s=0.f, s2=0.f;
                #pragma unroll
                for (int t=0; t<4; ++t){ float h = acc[t][rt][rr]; s += h; s2 += h*h; }
                p_[idx] = s; pp_[idx] = s2;
            }
            // fold over lane15: lane15==l ends with totals for idx l in [0]
            #pragma unroll
            for (int m=8; m>=1; m>>=1){
                const bool hi = (lane15 & m) != 0;
                #pragma unroll
                for (int i=0; i<m; ++i){
                    float sp = hi ? p_[i]  : p_[i+m];
                    float kp = hi ? p_[i+m]  : p_[i];
                    p_[i]  = kp + __shfl_xor(sp, m);
                    float sq = hi ? pp_[i] : pp_[i+m];
                    float kq = hi ? pp_[i+m] : pp_[i];
                    pp_[i] = kq + __shfl_xor(sq, m);
                }
            }
            int nd = (lane15>>2)*16 + q*4 + (lane15&3);
            atomicAdd(&stats[2*nd],   p_[0]);
            atomicAdd(&stats[2*nd+1], pp_[0]);
        }
        __syncthreads();   // stats final AND all GEMM1 xs reads drained

        // ---- Phase 3: LN2 + lrelu applied to acc in regs -> x2 into xs
        float g2c[4], b2c[4];
        #pragma unroll
        for (int t=0; t<4; ++t){
            int col = wv*64 + t*16 + lane15;
            g2c[t] = ln2g[col];
            b2c[t] = ln2b[col];
        }
        #pragma unroll
        for (int rt=0; rt<4; ++rt)
          #pragma unroll
          for (int rr=0; rr<4; ++rr){
            int nd = rt*16 + q*4 + rr;
            float mu   = stats[2*nd]*(1.f/1024.f);
            float rstd = rsqrtf(stats[2*nd+1]*(1.f/1024.f) - mu*mu + LN_EPS);
            #pragma unroll
            for (int t=0; t<4; ++t){
                float h = acc[t][rt][rr];
                float x = (h - mu)*rstd*g2c[t] + b2c[t];
                x = (x >= 0.f)? x : SLOPE*x;
                int col = wv*64 + t*16 + lane15;
                xs[(col>>3)*512 + nd*8 + (col&7)] = f2bf(x);
            }
          }
    }
    __syncthreads();

    // ---- Phase 4: h2 = x2 @ W2^T + b2, one pass (acc[4][4] live). Then two
    // staging rounds: round ps stages a-group wv*2+ps (tiles 2ps, 2ps+1) into
    // the retired xs region; one thread per (node, a): softmax + attn @ v.
    {
        f32x4 acc[4][4];
        gemm_quad1(Wp2, xs, wv*64, lane15, q, acc);
        float bias[4];
        #pragma unroll
        for (int t=0; t<4; ++t)
            bias[t] = b2[wv*64 + t*16 + lane15];
        __syncthreads();   // all xs reads complete before sbuf overwrite

        #pragma unroll
        for (int ps=0; ps<2; ++ps){
            // stage strip a = wv*2 + ps : sbuf[wv][node][b]
            #pragma unroll
            for (int ctl=0; ctl<2; ++ctl){
                const int t = ps*2 + ctl;
                #pragma unroll
                for (int rt=0; rt<4; ++rt)
                  #pragma unroll
                  for (int rr=0; rr<4; ++rr){
                    int nd = rt*16 + q*4 + rr;
                    sbuf[wv*SBS + nd*32 + ctl*16 + lane15] = acc[t][rt][rr] + bias[t];
                  }
            }
            __syncthreads();
            // consume: thread -> (node = tid>>4, slot s = tid&15, a = s*2+ps)
            {
                const int nd = tid >> 4;
                const int s  = tid & 15;
                const float* hp = sbuf + s*SBS + nd*32;
                float e[32];
                #pragma unroll
                for (int r=0;r<8;++r){
                    float4 v4 = ((const float4*)hp)[r];
                    e[4*r]=v4.x; e[4*r+1]=v4.y; e[4*r+2]=v4.z; e[4*r+3]=v4.w;
                }
                float mx = e[0];
                #pragma unroll
                for (int b=1;b<32;++b) mx = fmaxf(mx, e[b]);
                float sm = 0.f;
                #pragma unroll
                for (int b=0;b<32;++b){ e[b] = __expf(e[b]-mx); sm += e[b]; }
                float inv = 1.f / sm;
                float oacc[MDIM];
                #pragma unroll
                for (int c=0;c<MDIM;++c) oacc[c]=0.f;
                const float4* vr = (const float4*)(vbuf + nd*VSTR);
                #pragma unroll
                for (int r=0; r<8*MDIM; ++r){
                    float4 v4 = vr[r];
                    #pragma unroll
                    for (int t=0;t<4;++t){
                        const int fi = 4*r+t;
                        const int b  = fi/MDIM;
                        const int c  = fi - b*MDIM;
                        float comp = (t==0)?v4.x:(t==1)?v4.y:(t==2)?v4.z:v4.w;
                        oacc[c] += e[b]*comp;
                    }
                }
                int ng = node0 + nd;
                if (ng < NN){
                    const int a = s*2 + ps;
                    #pragma unroll
                    for (int c=0;c<MDIM;++c)
                        outp[((size_t)ng*32 + a)*MDIM + c] = oacc[c]*inv;
                }
            }
            if (ps==0) __syncthreads();   // WAR on sbuf before next stage
        }
    }
}

extern "C" void kernel_launch(void* const* d_in, const int* in_sizes, int n_in,
                              void* d_out, int out_size, void* d_ws, size_t ws_size,
                              hipStream_t stream)
{
    const float* f0    = (const float*)d_in[0];
    const float* f1    = (const float*)d_in[1];
    const float* ln1g0 = (const float*)d_in[2];
    const float* ln1b0 = (const float*)d_in[3];
    const float* w1_0  = (const float*)d_in[4];
    const float* ln2g0 = (const float*)d_in[5];
    const float* ln2b0 = (const float*)d_in[6];
    const float* w2_0  = (const float*)d_in[7];
    const float* b2_0  = (const float*)d_in[8];
    const float* ln1g1 = (const float*)d_in[9];
    const float* ln1b1 = (const float*)d_in[10];
    const float* w1_1  = (const float*)d_in[11];
    const float* ln2g1 = (const float*)d_in[12];
    const float* ln2b1 = (const float*)d_in[13];
    const float* w2_1  = (const float*)d_in[14];
    const float* b2_1  = (const float*)d_in[15];
    float* out = (float*)d_out;
    u16* wp = (u16*)d_ws;    // 4 packed matrices x 2 MB = 8 MB scratch

    const int smem1 = (32832 + 64*(32*1+4) + 128)*4;   // 141056
    const int smem3 = (32832 + 64*(32*3+4) + 128)*4;   // 157440
    (void)hipFuncSetAttribute(reinterpret_cast<const void*>(&gal_fused<1>),
                              hipFuncAttributeMaxDynamicSharedMemorySize, smem1);
    (void)hipFuncSetAttribute(reinterpret_cast<const void*>(&gal_fused<3>),
                              hipFuncAttributeMaxDynamicSharedMemorySize, smem3);

    prep_weights<<<dim3(128,4), 1024, 0, stream>>>(w1_0, w2_0, w1_1, w2_1, wp);
    gal_fused<1><<<NB, 1024, smem1, stream>>>(f0, ln1g0, ln1b0, ln2g0, ln2b0, b2_0,
                                              wp,            wp + 1048576, out);
    gal_fused<3><<<NB, 1024, smem3, stream>>>(f1, ln1g1, ln1b1, ln2g1, ln2b1, b2_1,
                                              wp + 2097152,  wp + 3145728, out + (size_t)NN*32);
}